// Round 1
// baseline (826.598 us; speedup 1.0000x reference)
//
#include <hip/hip_runtime.h>

// ---------------------------------------------------------------------------
// Fused equivariant FFN, bf16 MFMA (16x16x32), fp32 accumulate.
// N=200000 nodes, D_in = D_out = 480 fp32.
//   x0 (128) -> s=silu(x0@W0s*y/sqrt(128)+b_s) (384), g=sigmoid(x0@W0g..) (288)
//   o0 = s@V0 * y/sqrt(384) + b_o                       -> cols [0,128)
//   v1_m = (x1_m@W1) * y/8 * g[:192];  o1_m = v1_m@V1 * y/sqrt(192)  -> cols [128,320)
//   v2_m = (x2_m@W2) * y/sqrt(32) * g[192:]; o2_m = v2_m@V2 * y/sqrt(96) -> [320,480)
// One wave (64 threads) per block handles 16 nodes through all phases.
// ---------------------------------------------------------------------------

typedef __attribute__((ext_vector_type(8))) short short8;   // 8 bf16 = 4 VGPRs
typedef __attribute__((ext_vector_type(4))) float f32x4;

#define INV_M0f 0.08838834764831845f   // 1/sqrt(128)
#define INV_M1f 0.125f                 // 1/sqrt(64)
#define INV_M2f 0.17677669529663687f   // 1/sqrt(32)
#define INV_H0f 0.05103103630798288f   // 1/sqrt(384)
#define INV_H1f 0.07216878364870323f   // 1/sqrt(192)
#define INV_H2f 0.10206207261596577f   // 1/sqrt(96)

// packed bf16 weight offsets inside d_ws (units: shorts)
#define OFF_W0T 0         // [672][128]  W0T[j][k] = (j<384 ? W0s[k][j] : W0g[k][j-384])
#define OFF_W1T 86016     // [192][64]
#define OFF_W2T 98304     // [96][32]
#define OFF_V0T 101376    // [128][384]
#define OFF_V1T 150528    // [64][192]
#define OFF_V2T 162816    // [32][96]
#define WP_TOTAL 165888

__device__ __forceinline__ short f2bf(float f) {
    union { float f; unsigned u; } v; v.f = f;
    unsigned r = v.u + 0x7FFFu + ((v.u >> 16) & 1u);   // round-to-nearest-even
    return (short)(r >> 16);
}
__device__ __forceinline__ float bf2f(short s) {
    union { unsigned u; float f; } v; v.u = ((unsigned)(unsigned short)s) << 16;
    return v.f;
}

__global__ void prep_weights(const float* __restrict__ W0s, const float* __restrict__ W0g,
                             const float* __restrict__ W1,  const float* __restrict__ W2,
                             const float* __restrict__ V0,  const float* __restrict__ V1,
                             const float* __restrict__ V2,  short* __restrict__ ws)
{
    int i = blockIdx.x * 256 + threadIdx.x;
    if (i < 86016) {                    // W0T [672][128]
        int j = i >> 7, k = i & 127;
        float v = (j < 384) ? W0s[k * 384 + j] : W0g[k * 288 + (j - 384)];
        ws[i] = f2bf(v);
    } else if (i < 98304) {             // W1T [192][64]
        int e = i - 86016; int w = e >> 6, u = e & 63;
        ws[i] = f2bf(W1[u * 192 + w]);
    } else if (i < 101376) {            // W2T [96][32]
        int e = i - 98304; int w = e >> 5, u = e & 31;
        ws[i] = f2bf(W2[u * 96 + w]);
    } else if (i < 150528) {            // V0T [128][384]
        int e = i - 101376; int j = e / 384, w = e % 384;
        ws[i] = f2bf(V0[w * 128 + j]);
    } else if (i < 162816) {            // V1T [64][192]
        int e = i - 150528; int j = e / 192, w = e % 192;
        ws[i] = f2bf(V1[w * 64 + j]);
    } else if (i < WP_TOTAL) {          // V2T [32][96]
        int e = i - 162816; int j = e / 96, w = e % 96;
        ws[i] = f2bf(V2[w * 32 + j]);
    }
}

#define SB_STRIDE 392   // sbuf row stride (shorts), 384 + 8 pad (bank rotate)
#define XQ_STRIDE 200   // xq / ubuf row stride, 192 + 8 pad
#define GB_STRIDE 296   // gbuf row stride, 288 + 8 pad

#define MFMA(a, b, c) __builtin_amdgcn_mfma_f32_16x16x32_bf16((a), (b), (c), 0, 0, 0)

__global__ __launch_bounds__(64) void ffn_main(
    const float* __restrict__ X, const float* __restrict__ Y,
    const float* __restrict__ bs, const float* __restrict__ bg, const float* __restrict__ bo,
    const short* __restrict__ WP, float* __restrict__ out)
{
    // LDS (shorts): union{ sbuf[16*392]=6272 | xq[16*200]=3200 ++ ubuf[16*200]=3200 } ++ gbuf[16*296]
    __shared__ short lds[6400 + 16 * GB_STRIDE];
    short* sbuf = lds;
    short* xq   = lds;
    short* ubuf = lds + 3200;
    short* gbuf = lds + 6400;

    const int lane = threadIdx.x & 63;
    const int m  = lane & 15;     // A-row / B-col / D-col index
    const int bq = lane >> 4;     // k-block (A/B), D row-group
    const int n0 = blockIdx.x * 16;

    // y for the 4 output rows this lane owns (D rows = bq*4 + r)
    float y4[4];
    {
        const float* yp = Y + n0 + bq * 4;
        #pragma unroll
        for (int r = 0; r < 4; ++r) y4[r] = yp[r];
    }

    // ---- x0 A-fragments (16 nodes x 128 K) in registers ----
    short8 a0[4];
    {
        const float* xr = X + (size_t)(n0 + m) * 480 + bq * 8;
        #pragma unroll
        for (int k4 = 0; k4 < 4; ++k4) {
            float4 f0 = *(const float4*)(xr + k4 * 32);
            float4 f1 = *(const float4*)(xr + k4 * 32 + 4);
            short8 a;
            a[0]=f2bf(f0.x); a[1]=f2bf(f0.y); a[2]=f2bf(f0.z); a[3]=f2bf(f0.w);
            a[4]=f2bf(f1.x); a[5]=f2bf(f1.y); a[6]=f2bf(f1.z); a[7]=f2bf(f1.w);
            a0[k4] = a;
        }
    }

    // ---- Phase A: pre(16x672) = x0 @ W0T^T ; s -> sbuf, g -> gbuf ----
    #pragma unroll 1
    for (int jp = 0; jp < 21; ++jp) {
        const int jt0 = jp * 2;
        const short* w0 = WP + OFF_W0T + ((jt0 * 16 + m) * 128 + bq * 8);
        f32x4 acc0 = {0.f,0.f,0.f,0.f}, acc1 = {0.f,0.f,0.f,0.f};
        #pragma unroll
        for (int k4 = 0; k4 < 4; ++k4) {
            short8 b0 = *(const short8*)(w0 + k4 * 32);
            short8 b1 = *(const short8*)(w0 + 16 * 128 + k4 * 32);
            acc0 = MFMA(a0[k4], b0, acc0);
            acc1 = MFMA(a0[k4], b1, acc1);
        }
        #pragma unroll
        for (int t = 0; t < 2; ++t) {
            f32x4 acc = t ? acc1 : acc0;
            int j = (jt0 + t) * 16 + m;
            bool is_s = (j < 384);
            float bias = is_s ? bs[j] : bg[j - 384];
            #pragma unroll
            for (int r = 0; r < 4; ++r) {
                float val = acc[r] * (y4[r] * INV_M0f) + bias;
                float sig = 1.f / (1.f + __expf(-val));
                int node = bq * 4 + r;
                if (is_s) sbuf[node * SB_STRIDE + j]        = f2bf(val * sig); // silu
                else      gbuf[node * GB_STRIDE + (j - 384)] = f2bf(sig);      // sigmoid
            }
        }
    }
    __syncthreads();

    // ---- Phase D: o0(16x128) = s @ V0  (done now so sbuf can be reused) ----
    {
        short8 asD[12];
        #pragma unroll
        for (int k4 = 0; k4 < 12; ++k4)
            asD[k4] = *(const short8*)(sbuf + m * SB_STRIDE + k4 * 32 + bq * 8);
        #pragma unroll 1
        for (int jp = 0; jp < 4; ++jp) {
            const int jt0 = jp * 2;
            const short* v0 = WP + OFF_V0T + ((jt0 * 16 + m) * 384 + bq * 8);
            f32x4 acc0 = {0.f,0.f,0.f,0.f}, acc1 = {0.f,0.f,0.f,0.f};
            #pragma unroll
            for (int k4 = 0; k4 < 12; ++k4) {
                short8 b0 = *(const short8*)(v0 + k4 * 32);
                short8 b1 = *(const short8*)(v0 + 16 * 384 + k4 * 32);
                acc0 = MFMA(asD[k4], b0, acc0);
                acc1 = MFMA(asD[k4], b1, acc1);
            }
            #pragma unroll
            for (int t = 0; t < 2; ++t) {
                f32x4 acc = t ? acc1 : acc0;
                int j = (jt0 + t) * 16 + m;
                float bj = bo[j];
                #pragma unroll
                for (int r = 0; r < 4; ++r) {
                    float val = acc[r] * (y4[r] * INV_H0f) + bj;
                    out[(size_t)(n0 + bq * 4 + r) * 480 + j] = val;
                }
            }
        }
    }
    __syncthreads();

    // ---- stage x1 (cols 128..319) as bf16 into xq ----
    for (int idx = lane; idx < 16 * 48; idx += 64) {
        int row = idx / 48, c = idx % 48;
        float4 f = *(const float4*)(X + (size_t)(n0 + row) * 480 + 128 + c * 4);
        short4 s4; s4.x=f2bf(f.x); s4.y=f2bf(f.y); s4.z=f2bf(f.z); s4.w=f2bf(f.w);
        *(short4*)(xq + row * XQ_STRIDE + c * 4) = s4;
    }
    __syncthreads();

    // ---- Phase B1: 3 vector components through W1 (gate) then V1 ----
    #pragma unroll 1
    for (int mm = 0; mm < 3; ++mm) {
        short8 a1[2];
        #pragma unroll
        for (int k4 = 0; k4 < 2; ++k4) {
            short8 a;
            #pragma unroll
            for (int i = 0; i < 8; ++i)
                a[i] = xq[m * XQ_STRIDE + (k4 * 32 + bq * 8 + i) * 3 + mm];
            a1[k4] = a;
        }
        // GEMM1: t(16x192) = x1_mm @ W1, gated -> ubuf (bf16)
        #pragma unroll 1
        for (int jp = 0; jp < 6; ++jp) {
            const int jt0 = jp * 2;
            const short* w1 = WP + OFF_W1T + ((jt0 * 16 + m) * 64 + bq * 8);
            f32x4 acc0 = {0.f,0.f,0.f,0.f}, acc1 = {0.f,0.f,0.f,0.f};
            #pragma unroll
            for (int k4 = 0; k4 < 2; ++k4) {
                acc0 = MFMA(a1[k4], *(const short8*)(w1 + k4 * 32), acc0);
                acc1 = MFMA(a1[k4], *(const short8*)(w1 + 16 * 64 + k4 * 32), acc1);
            }
            #pragma unroll
            for (int t = 0; t < 2; ++t) {
                f32x4 acc = t ? acc1 : acc0;
                int w = (jt0 + t) * 16 + m;
                #pragma unroll
                for (int r = 0; r < 4; ++r) {
                    int node = bq * 4 + r;
                    float gv = bf2f(gbuf[node * GB_STRIDE + w]);
                    ubuf[node * XQ_STRIDE + w] = f2bf(acc[r] * (y4[r] * INV_M1f) * gv);
                }
            }
        }
        __syncthreads();
        // GEMM2: o1_mm(16x64) = u @ V1
        short8 au[6];
        #pragma unroll
        for (int k4 = 0; k4 < 6; ++k4)
            au[k4] = *(const short8*)(ubuf + m * XQ_STRIDE + k4 * 32 + bq * 8);
        #pragma unroll 1
        for (int jp = 0; jp < 2; ++jp) {
            const int jt0 = jp * 2;
            const short* v1 = WP + OFF_V1T + ((jt0 * 16 + m) * 192 + bq * 8);
            f32x4 acc0 = {0.f,0.f,0.f,0.f}, acc1 = {0.f,0.f,0.f,0.f};
            #pragma unroll
            for (int k4 = 0; k4 < 6; ++k4) {
                acc0 = MFMA(au[k4], *(const short8*)(v1 + k4 * 32), acc0);
                acc1 = MFMA(au[k4], *(const short8*)(v1 + 16 * 192 + k4 * 32), acc1);
            }
            #pragma unroll
            for (int t = 0; t < 2; ++t) {
                f32x4 acc = t ? acc1 : acc0;
                int j = (jt0 + t) * 16 + m;
                #pragma unroll
                for (int r = 0; r < 4; ++r)
                    out[(size_t)(n0 + bq * 4 + r) * 480 + 128 + j * 3 + mm] =
                        acc[r] * (y4[r] * INV_H1f);
            }
        }
        __syncthreads();
    }

    // ---- stage x2 (cols 320..479) as bf16 into xq ----
    for (int idx = lane; idx < 16 * 40; idx += 64) {
        int row = idx / 40, c = idx % 40;
        float4 f = *(const float4*)(X + (size_t)(n0 + row) * 480 + 320 + c * 4);
        short4 s4; s4.x=f2bf(f.x); s4.y=f2bf(f.y); s4.z=f2bf(f.z); s4.w=f2bf(f.w);
        *(short4*)(xq + row * XQ_STRIDE + c * 4) = s4;
    }
    __syncthreads();

    // ---- Phase B2: 5 components through W2 (gate) then V2 ----
    #pragma unroll 1
    for (int mm = 0; mm < 5; ++mm) {
        short8 a2;
        #pragma unroll
        for (int i = 0; i < 8; ++i)
            a2[i] = xq[m * XQ_STRIDE + (bq * 8 + i) * 5 + mm];
        // GEMM1: t2(16x96) = x2_mm @ W2 (K=32, single k-tile), gated -> ubuf
        #pragma unroll 1
        for (int jp = 0; jp < 3; ++jp) {
            const int jt0 = jp * 2;
            const short* w2 = WP + OFF_W2T + ((jt0 * 16 + m) * 32 + bq * 8);
            f32x4 z = {0.f,0.f,0.f,0.f};
            f32x4 acc0 = MFMA(a2, *(const short8*)(w2), z);
            f32x4 acc1 = MFMA(a2, *(const short8*)(w2 + 16 * 32), z);
            #pragma unroll
            for (int t = 0; t < 2; ++t) {
                f32x4 acc = t ? acc1 : acc0;
                int w = (jt0 + t) * 16 + m;
                #pragma unroll
                for (int r = 0; r < 4; ++r) {
                    int node = bq * 4 + r;
                    float gv = bf2f(gbuf[node * GB_STRIDE + 192 + w]);
                    ubuf[node * XQ_STRIDE + w] = f2bf(acc[r] * (y4[r] * INV_M2f) * gv);
                }
            }
        }
        __syncthreads();
        // GEMM2: o2_mm(16x32) = u2 @ V2 (K=96)
        short8 au2[3];
        #pragma unroll
        for (int k4 = 0; k4 < 3; ++k4)
            au2[k4] = *(const short8*)(ubuf + m * XQ_STRIDE + k4 * 32 + bq * 8);
        {
            const short* v2 = WP + OFF_V2T + (m * 96 + bq * 8);
            f32x4 acc0 = {0.f,0.f,0.f,0.f}, acc1 = {0.f,0.f,0.f,0.f};
            #pragma unroll
            for (int k4 = 0; k4 < 3; ++k4) {
                acc0 = MFMA(au2[k4], *(const short8*)(v2 + k4 * 32), acc0);
                acc1 = MFMA(au2[k4], *(const short8*)(v2 + 16 * 96 + k4 * 32), acc1);
            }
            #pragma unroll
            for (int t = 0; t < 2; ++t) {
                f32x4 acc = t ? acc1 : acc0;
                int j = t * 16 + m;
                #pragma unroll
                for (int r = 0; r < 4; ++r)
                    out[(size_t)(n0 + bq * 4 + r) * 480 + 320 + j * 5 + mm] =
                        acc[r] * (y4[r] * INV_H2f);
            }
        }
        __syncthreads();
    }
}

extern "C" void kernel_launch(void* const* d_in, const int* in_sizes, int n_in,
                              void* d_out, int out_size, void* d_ws, size_t ws_size,
                              hipStream_t stream)
{
    const float* X   = (const float*)d_in[0];
    const float* Y   = (const float*)d_in[1];
    const float* W0s = (const float*)d_in[2];
    const float* bs  = (const float*)d_in[3];
    const float* W0g = (const float*)d_in[4];
    const float* bg  = (const float*)d_in[5];
    const float* W1  = (const float*)d_in[6];
    const float* W2  = (const float*)d_in[7];
    const float* V0  = (const float*)d_in[8];
    const float* bo  = (const float*)d_in[9];
    const float* V1  = (const float*)d_in[10];
    const float* V2  = (const float*)d_in[11];
    short* WP  = (short*)d_ws;           // 331776 B of bf16-packed weights
    float* out = (float*)d_out;

    const int n = in_sizes[0] / 480;     // 200000 (divisible by 16)
    const int tiles = n / 16;            // 12500 wave-tiles

    prep_weights<<<dim3((WP_TOTAL + 255) / 256), dim3(256), 0, stream>>>(
        W0s, W0g, W1, W2, V0, V1, V2, WP);
    ffn_main<<<dim3(tiles), dim3(64), 0, stream>>>(X, Y, bs, bg, bo, WP, out);
}

// Round 3
// 663.967 us; speedup vs baseline: 1.2449x; 1.2449x over previous
//
#include <hip/hip_runtime.h>

// ---------------------------------------------------------------------------
// Fused equivariant FFN, bf16 MFMA (16x16x32), fp32 accumulate.
// Round 3 = round 2 with the x0s LDS stride bug fixed (72 -> 136).
// 4 waves/block cooperate on one 16-node group, splitting the output-column
// (j) dimension of every GEMM. x0 staged once to LDS; x1/x2 staged
// pre-transposed [mm][node][u] so MFMA A-fragments are vector ds_read_b128.
// ---------------------------------------------------------------------------

typedef __attribute__((ext_vector_type(8))) short short8;   // 8 bf16 = 4 VGPRs
typedef __attribute__((ext_vector_type(4))) float f32x4;

#define INV_M0f 0.08838834764831845f   // 1/sqrt(128)
#define INV_M1f 0.125f                 // 1/sqrt(64)
#define INV_M2f 0.17677669529663687f   // 1/sqrt(32)
#define INV_H0f 0.05103103630798288f   // 1/sqrt(384)
#define INV_H1f 0.07216878364870323f   // 1/sqrt(192)
#define INV_H2f 0.10206207261596577f   // 1/sqrt(96)

// packed bf16 weight offsets inside d_ws (units: shorts)
#define OFF_W0T 0         // [672][128]  W0T[j][k] = (j<384 ? W0s[k][j] : W0g[k][j-384])
#define OFF_W1T 86016     // [192][64]
#define OFF_W2T 98304     // [96][32]
#define OFF_V0T 101376    // [128][384]
#define OFF_V1T 150528    // [64][192]
#define OFF_V2T 162816    // [32][96]
#define WP_TOTAL 165888

__device__ __forceinline__ short f2bf(float f) {
    union { float f; unsigned u; } v; v.f = f;
    unsigned r = v.u + 0x7FFFu + ((v.u >> 16) & 1u);   // round-to-nearest-even
    return (short)(r >> 16);
}
__device__ __forceinline__ float bf2f(short s) {
    union { unsigned u; float f; } v; v.u = ((unsigned)(unsigned short)s) << 16;
    return v.f;
}

__global__ void prep_weights(const float* __restrict__ W0s, const float* __restrict__ W0g,
                             const float* __restrict__ W1,  const float* __restrict__ W2,
                             const float* __restrict__ V0,  const float* __restrict__ V1,
                             const float* __restrict__ V2,  short* __restrict__ ws)
{
    int i = blockIdx.x * 256 + threadIdx.x;
    if (i < 86016) {                    // W0T [672][128]
        int j = i >> 7, k = i & 127;
        float v = (j < 384) ? W0s[k * 384 + j] : W0g[k * 288 + (j - 384)];
        ws[i] = f2bf(v);
    } else if (i < 98304) {             // W1T [192][64]
        int e = i - 86016; int w = e >> 6, u = e & 63;
        ws[i] = f2bf(W1[u * 192 + w]);
    } else if (i < 101376) {            // W2T [96][32]
        int e = i - 98304; int w = e >> 5, u = e & 31;
        ws[i] = f2bf(W2[u * 96 + w]);
    } else if (i < 150528) {            // V0T [128][384]
        int e = i - 101376; int j = e / 384, w = e % 384;
        ws[i] = f2bf(V0[w * 128 + j]);
    } else if (i < 162816) {            // V1T [64][192]
        int e = i - 150528; int j = e / 192, w = e % 192;
        ws[i] = f2bf(V1[w * 64 + j]);
    } else if (i < WP_TOTAL) {          // V2T [32][96]
        int e = i - 162816; int j = e / 96, w = e % 96;
        ws[i] = f2bf(V2[w * 32 + j]);
    }
}

// ---- LDS layout (shorts), total 13184 shorts = 26368 B ----
// x0s  @     0 : [16][136] = 2176   (live: start -> end Phase A)
// sbuf @  2176 : [16][392] = 6272   (live: Phase A -> Phase D)   [2176, 8448)
// gbuf @  8448 : [16][296] = 4736   (live: Phase A -> end)       [8448,13184)
// x1T  @     0 : [3][16][72] = 3456 (after D; overlays dead x0s + sbuf head)
// x2T  @     0 : [5][16][40] = 3200 (after B1)
// ubuf @  3456 : [16][200] = 3200   (B phases; overlays dead sbuf) [3456,6656)
#define X0_STRIDE 136
#define SB_OFF 2176
#define GB_OFF 8448
#define UB_OFF 3456
#define SB_STRIDE 392
#define GB_STRIDE 296
#define UB_STRIDE 200

#define MFMA(a, b, c) __builtin_amdgcn_mfma_f32_16x16x32_bf16((a), (b), (c), 0, 0, 0)

__global__ __launch_bounds__(256, 5) void ffn_main(
    const float* __restrict__ X, const float* __restrict__ Y,
    const float* __restrict__ bs, const float* __restrict__ bg, const float* __restrict__ bo,
    const short* __restrict__ WP, float* __restrict__ out)
{
    __shared__ short lds[13184];
    short* x0s  = lds;
    short* sbuf = lds + SB_OFF;
    short* gbuf = lds + GB_OFF;
    short* x1T  = lds;
    short* x2T  = lds;
    short* ubuf = lds + UB_OFF;

    const int tid  = threadIdx.x;
    const int wid  = tid >> 6;     // wave 0..3
    const int lane = tid & 63;
    const int m    = lane & 15;    // A-row / B-col / D-col index
    const int bq   = lane >> 4;    // k-block (A/B), D row-group
    const int n0   = blockIdx.x * 16;

    // ---- stage x0 (16 nodes x 128 cols) -> LDS bf16, coalesced ----
    {
        const int node = tid >> 4, c16 = tid & 15;
        const float* xp = X + (size_t)(n0 + node) * 480 + c16 * 8;
        float4 f0 = *(const float4*)xp;
        float4 f1 = *(const float4*)(xp + 4);
        short8 a;
        a[0]=f2bf(f0.x); a[1]=f2bf(f0.y); a[2]=f2bf(f0.z); a[3]=f2bf(f0.w);
        a[4]=f2bf(f1.x); a[5]=f2bf(f1.y); a[6]=f2bf(f1.z); a[7]=f2bf(f1.w);
        *(short8*)(x0s + node * X0_STRIDE + c16 * 8) = a;
    }
    __syncthreads();

    // y for the 4 output rows this lane owns (D rows = bq*4 + r)
    float y4[4];
    {
        const float* yp = Y + n0 + bq * 4;
        #pragma unroll
        for (int r = 0; r < 4; ++r) y4[r] = yp[r];
    }

    // x0 A-fragments from LDS
    short8 a0[4];
    #pragma unroll
    for (int k4 = 0; k4 < 4; ++k4)
        a0[k4] = *(const short8*)(x0s + m * X0_STRIDE + k4 * 32 + bq * 8);

    // ---- Phase A: pre(16x672) = x0 @ W0T^T ; s -> sbuf, g -> gbuf ----
    // 21 j-tile-pairs split across 4 waves
    #pragma unroll 1
    for (int jp = wid; jp < 21; jp += 4) {
        const int jt0 = jp * 2;
        const short* w0 = WP + OFF_W0T + ((jt0 * 16 + m) * 128 + bq * 8);
        f32x4 acc0 = {0.f,0.f,0.f,0.f}, acc1 = {0.f,0.f,0.f,0.f};
        #pragma unroll
        for (int k4 = 0; k4 < 4; ++k4) {
            short8 b0 = *(const short8*)(w0 + k4 * 32);
            short8 b1 = *(const short8*)(w0 + 16 * 128 + k4 * 32);
            acc0 = MFMA(a0[k4], b0, acc0);
            acc1 = MFMA(a0[k4], b1, acc1);
        }
        #pragma unroll
        for (int t = 0; t < 2; ++t) {
            f32x4 acc = t ? acc1 : acc0;
            int j = (jt0 + t) * 16 + m;
            bool is_s = (j < 384);
            float bias = is_s ? bs[j] : bg[j - 384];
            #pragma unroll
            for (int r = 0; r < 4; ++r) {
                float val = acc[r] * (y4[r] * INV_M0f) + bias;
                float sig = 1.f / (1.f + __expf(-val));
                int node = bq * 4 + r;
                if (is_s) sbuf[node * SB_STRIDE + j]         = f2bf(val * sig); // silu
                else      gbuf[node * GB_STRIDE + (j - 384)] = f2bf(sig);       // sigmoid
            }
        }
    }
    __syncthreads();

    // ---- Phase D: o0(16x128) = s @ V0 ; 4 j-pairs, one per wave ----
    {
        const int jt0 = wid * 2;
        const short* v0 = WP + OFF_V0T + ((jt0 * 16 + m) * 384 + bq * 8);
        f32x4 acc0 = {0.f,0.f,0.f,0.f}, acc1 = {0.f,0.f,0.f,0.f};
        #pragma unroll 1
        for (int kc = 0; kc < 2; ++kc) {
            #pragma unroll
            for (int k4i = 0; k4i < 6; ++k4i) {
                int k4 = kc * 6 + k4i;
                short8 a = *(const short8*)(sbuf + m * SB_STRIDE + k4 * 32 + bq * 8);
                acc0 = MFMA(a, *(const short8*)(v0 + k4 * 32), acc0);
                acc1 = MFMA(a, *(const short8*)(v0 + 16 * 384 + k4 * 32), acc1);
            }
        }
        #pragma unroll
        for (int t = 0; t < 2; ++t) {
            f32x4 acc = t ? acc1 : acc0;
            int j = (jt0 + t) * 16 + m;
            float bj = bo[j];
            #pragma unroll
            for (int r = 0; r < 4; ++r)
                out[(size_t)(n0 + bq * 4 + r) * 480 + j] = acc[r] * (y4[r] * INV_H0f) + bj;
        }
    }
    __syncthreads();

    // ---- stage x1 transposed: x1T[mm][node][u], u in [0,64) pad 72 ----
    {
        const int node = tid >> 4, c16 = tid & 15;
        const float* xp = X + (size_t)(n0 + node) * 480 + 128 + c16 * 12;
        float4 fa = *(const float4*)xp;
        float4 fb = *(const float4*)(xp + 4);
        float4 fc = *(const float4*)(xp + 8);
        float vals[12] = {fa.x,fa.y,fa.z,fa.w, fb.x,fb.y,fb.z,fb.w, fc.x,fc.y,fc.z,fc.w};
        #pragma unroll
        for (int c = 0; c < 12; ++c) {
            int col = c16 * 12 + c;
            int u = col / 3, mmv = col % 3;
            x1T[mmv * 1152 + node * 72 + u] = f2bf(vals[c]);
        }
    }
    __syncthreads();

    // ---- Phase B1: 3 vector components through W1 (gate) then V1 ----
    #pragma unroll 1
    for (int mm = 0; mm < 3; ++mm) {
        short8 a1[2];
        #pragma unroll
        for (int k4 = 0; k4 < 2; ++k4)
            a1[k4] = *(const short8*)(x1T + mm * 1152 + m * 72 + k4 * 32 + bq * 8);
        // GEMM1: t(16x192) = x1_mm @ W1, gated -> ubuf ; 6 pairs over 4 waves
        #pragma unroll 1
        for (int jp = wid; jp < 6; jp += 4) {
            const int jt0 = jp * 2;
            const short* w1 = WP + OFF_W1T + ((jt0 * 16 + m) * 64 + bq * 8);
            f32x4 acc0 = {0.f,0.f,0.f,0.f}, acc1 = {0.f,0.f,0.f,0.f};
            #pragma unroll
            for (int k4 = 0; k4 < 2; ++k4) {
                acc0 = MFMA(a1[k4], *(const short8*)(w1 + k4 * 32), acc0);
                acc1 = MFMA(a1[k4], *(const short8*)(w1 + 16 * 64 + k4 * 32), acc1);
            }
            #pragma unroll
            for (int t = 0; t < 2; ++t) {
                f32x4 acc = t ? acc1 : acc0;
                int w = (jt0 + t) * 16 + m;
                #pragma unroll
                for (int r = 0; r < 4; ++r) {
                    int node = bq * 4 + r;
                    float gv = bf2f(gbuf[node * GB_STRIDE + w]);
                    ubuf[node * UB_STRIDE + w] = f2bf(acc[r] * (y4[r] * INV_M1f) * gv);
                }
            }
        }
        __syncthreads();
        // GEMM2: o1_mm(16x64) = u @ V1 ; 4 tiles, one per wave
        {
            const int jt = wid;
            const short* v1 = WP + OFF_V1T + ((jt * 16 + m) * 192 + bq * 8);
            f32x4 acc = {0.f,0.f,0.f,0.f};
            #pragma unroll
            for (int k4 = 0; k4 < 6; ++k4) {
                short8 a = *(const short8*)(ubuf + m * UB_STRIDE + k4 * 32 + bq * 8);
                acc = MFMA(a, *(const short8*)(v1 + k4 * 32), acc);
            }
            int j = jt * 16 + m;
            #pragma unroll
            for (int r = 0; r < 4; ++r)
                out[(size_t)(n0 + bq * 4 + r) * 480 + 128 + j * 3 + mm] =
                    acc[r] * (y4[r] * INV_H1f);
        }
        __syncthreads();
    }

    // ---- stage x2 transposed: x2T[mm][node][u], u in [0,32) pad 40 ----
    {
        const int node = tid >> 4, c16 = tid & 15;
        const float* xp = X + (size_t)(n0 + node) * 480 + 320 + c16 * 10;
        float vals[10];
        #pragma unroll
        for (int p = 0; p < 5; ++p) {
            float2 f = *(const float2*)(xp + p * 2);
            vals[p * 2] = f.x; vals[p * 2 + 1] = f.y;
        }
        #pragma unroll
        for (int c = 0; c < 10; ++c) {
            int col = c16 * 10 + c;
            int u = col / 5, mmv = col % 5;
            x2T[mmv * 640 + node * 40 + u] = f2bf(vals[c]);
        }
    }
    __syncthreads();

    // ---- Phase B2: 5 components through W2 (gate) then V2 ----
    #pragma unroll 1
    for (int mm = 0; mm < 5; ++mm) {
        short8 a2 = *(const short8*)(x2T + mm * 640 + m * 40 + bq * 8);
        // GEMM1: t2(16x96) = x2_mm @ W2, gated -> ubuf ; 6 tiles over 4 waves
        #pragma unroll 1
        for (int jt = wid; jt < 6; jt += 4) {
            const short* w2 = WP + OFF_W2T + ((jt * 16 + m) * 32 + bq * 8);
            f32x4 z = {0.f,0.f,0.f,0.f};
            f32x4 acc = MFMA(a2, *(const short8*)w2, z);
            int w = jt * 16 + m;
            #pragma unroll
            for (int r = 0; r < 4; ++r) {
                int node = bq * 4 + r;
                float gv = bf2f(gbuf[node * GB_STRIDE + 192 + w]);
                ubuf[node * UB_STRIDE + w] = f2bf(acc[r] * (y4[r] * INV_M2f) * gv);
            }
        }
        __syncthreads();
        // GEMM2: o2_mm(16x32) = u2 @ V2 (K=96) ; 2 tiles on waves 0,1
        if (wid < 2) {
            const int jt = wid;
            const short* v2 = WP + OFF_V2T + ((jt * 16 + m) * 96 + bq * 8);
            f32x4 acc = {0.f,0.f,0.f,0.f};
            #pragma unroll
            for (int k4 = 0; k4 < 3; ++k4) {
                short8 a = *(const short8*)(ubuf + m * UB_STRIDE + k4 * 32 + bq * 8);
                acc = MFMA(a, *(const short8*)(v2 + k4 * 32), acc);
            }
            int j = jt * 16 + m;
            #pragma unroll
            for (int r = 0; r < 4; ++r)
                out[(size_t)(n0 + bq * 4 + r) * 480 + 320 + j * 5 + mm] =
                    acc[r] * (y4[r] * INV_H2f);
        }
        __syncthreads();
    }
}

extern "C" void kernel_launch(void* const* d_in, const int* in_sizes, int n_in,
                              void* d_out, int out_size, void* d_ws, size_t ws_size,
                              hipStream_t stream)
{
    const float* X   = (const float*)d_in[0];
    const float* Y   = (const float*)d_in[1];
    const float* W0s = (const float*)d_in[2];
    const float* bs  = (const float*)d_in[3];
    const float* W0g = (const float*)d_in[4];
    const float* bg  = (const float*)d_in[5];
    const float* W1  = (const float*)d_in[6];
    const float* W2  = (const float*)d_in[7];
    const float* V0  = (const float*)d_in[8];
    const float* bo  = (const float*)d_in[9];
    const float* V1  = (const float*)d_in[10];
    const float* V2  = (const float*)d_in[11];
    short* WP  = (short*)d_ws;           // 331776 B of bf16-packed weights
    float* out = (float*)d_out;

    const int n = in_sizes[0] / 480;     // 200000 (divisible by 16)
    const int tiles = n / 16;            // 12500 16-node tiles

    prep_weights<<<dim3((WP_TOTAL + 255) / 256), dim3(256), 0, stream>>>(
        W0s, W0g, W1, W2, V0, V1, V2, WP);
    ffn_main<<<dim3(tiles), dim3(256), 0, stream>>>(X, Y, bs, bg, bo, WP, out);
}

// Round 4
// 334.127 us; speedup vs baseline: 2.4739x; 1.9872x over previous
//
#include <hip/hip_runtime.h>

// ---------------------------------------------------------------------------
// Fused equivariant FFN, bf16 MFMA (16x16x32), fp32 accumulate.
// Round 4: 32 nodes/block, 8 waves, 2 row-tiles/wave (MFMA:B-load = 2:1),
// software-pipelined weight loads (prefetch next j-tile / prefetch across
// barriers), INV_* constants folded into prepacked weights, 1-op bf16 cvt
// via v_cvt_pk_bf16_f32, o1/o2 register-accumulated across mm for dense
// stores (kills write amplification).
// ---------------------------------------------------------------------------

typedef __attribute__((ext_vector_type(8))) short short8;   // 8 bf16 = 4 VGPRs
typedef __attribute__((ext_vector_type(4))) float f32x4;

#define INV_M0f 0.08838834764831845f   // 1/sqrt(128)
#define INV_M1f 0.125f                 // 1/sqrt(64)
#define INV_M2f 0.17677669529663687f   // 1/sqrt(32)
#define INV_H0f 0.05103103630798288f   // 1/sqrt(384)
#define INV_H1f 0.07216878364870323f   // 1/sqrt(192)
#define INV_H2f 0.10206207261596577f   // 1/sqrt(96)

// packed bf16 weight offsets inside d_ws (units: shorts). All prescaled by
// their INV_* constant so epilogues do val = fma(acc, y, bias) / acc*y.
#define OFF_W0T 0         // [672][128]  (W0s|W0g)^T * INV_M0
#define OFF_W1T 86016     // [192][64]   W1^T * INV_M1
#define OFF_W2T 98304     // [96][32]    W2^T * INV_M2
#define OFF_V0T 101376    // [128][384]  V0^T * INV_H0
#define OFF_V1T 150528    // [64][192]   V1^T * INV_H1
#define OFF_V2T 162816    // [32][96]    V2^T * INV_H2
#define WP_TOTAL 165888

__device__ __forceinline__ short f2bf_rne(float f) {        // prep only
    union { float f; unsigned u; } v; v.f = f;
    unsigned r = v.u + 0x7FFFu + ((v.u >> 16) & 1u);
    return (short)(r >> 16);
}
// 1-VALU bf16 convert (RNE) for the hot kernel
__device__ __forceinline__ short f2bf_fast(float f) {
    unsigned r;
    asm("v_cvt_pk_bf16_f32 %0, %1, %1" : "=v"(r) : "v"(f));
    return (short)r;
}
__device__ __forceinline__ float bf2f(short s) {
    union { unsigned u; float f; } v; v.u = ((unsigned)(unsigned short)s) << 16;
    return v.f;
}

__global__ void prep_weights(const float* __restrict__ W0s, const float* __restrict__ W0g,
                             const float* __restrict__ W1,  const float* __restrict__ W2,
                             const float* __restrict__ V0,  const float* __restrict__ V1,
                             const float* __restrict__ V2,  short* __restrict__ ws)
{
    int i = blockIdx.x * 256 + threadIdx.x;
    if (i < 86016) {                    // W0T [672][128]
        int j = i >> 7, k = i & 127;
        float v = (j < 384) ? W0s[k * 384 + j] : W0g[k * 288 + (j - 384)];
        ws[i] = f2bf_rne(v * INV_M0f);
    } else if (i < 98304) {             // W1T [192][64]
        int e = i - 86016; int w = e >> 6, u = e & 63;
        ws[i] = f2bf_rne(W1[u * 192 + w] * INV_M1f);
    } else if (i < 101376) {            // W2T [96][32]
        int e = i - 98304; int w = e >> 5, u = e & 31;
        ws[i] = f2bf_rne(W2[u * 96 + w] * INV_M2f);
    } else if (i < 150528) {            // V0T [128][384]
        int e = i - 101376; int j = e / 384, w = e % 384;
        ws[i] = f2bf_rne(V0[w * 128 + j] * INV_H0f);
    } else if (i < 162816) {            // V1T [64][192]
        int e = i - 150528; int j = e / 192, w = e % 192;
        ws[i] = f2bf_rne(V1[w * 64 + j] * INV_H1f);
    } else if (i < WP_TOTAL) {          // V2T [32][96]
        int e = i - 162816; int j = e / 96, w = e % 96;
        ws[i] = f2bf_rne(V2[w * 32 + j] * INV_H2f);
    }
}

// ---- LDS layout (shorts), 32 nodes, total 26368 shorts = 52736 B ----
// x0s  @     0 : [32][136] = 4352   (start -> end Phase A)
// sbuf @  4352 : [32][392] = 12544  (Phase A -> Phase D)    [4352,16896)
// gbuf @ 16896 : [32][296] = 9472   (Phase A -> end)        [16896,26368)
// x1T  @     0 : [3][32][72] = 6912 (after D; overlays dead x0s+sbuf head)
// x2T  @     0 : [5][32][40] = 6400 (after B1; overlays dead x1T)
// ubuf @  6912 : [32][200] = 6400   (B phases; overlays dead sbuf) [6912,13312)
#define X0_STRIDE 136
#define SB_OFF 4352
#define SB_STRIDE 392
#define GB_OFF 16896
#define GB_STRIDE 296
#define UB_OFF 6912
#define UB_STRIDE 200
#define LDS_SHORTS 26368

#define MFMA(a, b, c) __builtin_amdgcn_mfma_f32_16x16x32_bf16((a), (b), (c), 0, 0, 0)

__global__ __launch_bounds__(512, 4) void ffn_main(
    const float* __restrict__ X, const float* __restrict__ Y,
    const float* __restrict__ bs, const float* __restrict__ bg, const float* __restrict__ bo,
    const short* __restrict__ WP, float* __restrict__ out)
{
    __shared__ short lds[LDS_SHORTS];
    short* x0s  = lds;
    short* sbuf = lds + SB_OFF;
    short* gbuf = lds + GB_OFF;
    short* x1T  = lds;
    short* x2T  = lds;
    short* ubuf = lds + UB_OFF;

    const int tid  = threadIdx.x;
    const int wid  = tid >> 6;     // wave 0..7
    const int lane = tid & 63;
    const int m    = lane & 15;    // A-row(node) / B-row(out-col) index
    const int bq   = lane >> 4;    // k-block; D row-group
    const int n0   = blockIdx.x * 32;

    // ---- prefetch first Phase-A weight tile (overlaps x0 staging) ----
    short8 w0c[4];
    float bias_c;
    {
        const short* w = WP + OFF_W0T + (wid * 16 + m) * 128 + bq * 8;
        #pragma unroll
        for (int k = 0; k < 4; ++k) w0c[k] = *(const short8*)(w + k * 32);
        bias_c = bs[wid * 16 + m];          // first jt = wid < 24 -> always bs
    }

    // ---- stage x0 (32 nodes x 128 cols) -> LDS bf16, coalesced ----
    {
        const int node = tid >> 4, c16 = tid & 15;
        const float* xp = X + (size_t)(n0 + node) * 480 + c16 * 8;
        float4 f0 = *(const float4*)xp;
        float4 f1 = *(const float4*)(xp + 4);
        short8 a;
        a[0]=f2bf_fast(f0.x); a[1]=f2bf_fast(f0.y); a[2]=f2bf_fast(f0.z); a[3]=f2bf_fast(f0.w);
        a[4]=f2bf_fast(f1.x); a[5]=f2bf_fast(f1.y); a[6]=f2bf_fast(f1.z); a[7]=f2bf_fast(f1.w);
        *(short8*)(x0s + node * X0_STRIDE + c16 * 8) = a;
    }

    // y for the 8 output rows this lane touches: rows t*16 + bq*4 + r
    float yv[2][4];
    #pragma unroll
    for (int t = 0; t < 2; ++t)
        #pragma unroll
        for (int r = 0; r < 4; ++r)
            yv[t][r] = Y[n0 + t * 16 + bq * 4 + r];

    __syncthreads();

    // x0 A-fragments, both row-tiles
    short8 a0[2][4];
    #pragma unroll
    for (int t = 0; t < 2; ++t)
        #pragma unroll
        for (int k = 0; k < 4; ++k)
            a0[t][k] = *(const short8*)(x0s + (t * 16 + m) * X0_STRIDE + k * 32 + bq * 8);

    // ---- Phase A: pre(32x672) = x0 @ W0T^T ; s -> sbuf, g -> gbuf ----
    // jt = wid + 8i, software-pipelined B-fragments (1 tile ahead)
    #pragma unroll 1
    for (int i = 0; i < 6; ++i) {
        const int jt = wid + i * 8;
        if (jt >= 42) break;
        const int jn = jt + 8;
        short8 w0n[4];
        float bias_n = 0.f;
        if (jn < 42) {
            const short* w = WP + OFF_W0T + (jn * 16 + m) * 128 + bq * 8;
            #pragma unroll
            for (int k = 0; k < 4; ++k) w0n[k] = *(const short8*)(w + k * 32);
            bias_n = (jn < 24) ? bs[jn * 16 + m] : bg[(jn - 24) * 16 + m];
        }
        f32x4 acc0 = {0.f,0.f,0.f,0.f}, acc1 = {0.f,0.f,0.f,0.f};
        #pragma unroll
        for (int k = 0; k < 4; ++k) {
            acc0 = MFMA(a0[0][k], w0c[k], acc0);
            acc1 = MFMA(a0[1][k], w0c[k], acc1);
        }
        if (jt < 24) {          // silu -> sbuf, col j = jt*16+m
            #pragma unroll
            for (int t = 0; t < 2; ++t) {
                f32x4 acc = t ? acc1 : acc0;
                #pragma unroll
                for (int r = 0; r < 4; ++r) {
                    float val = fmaf(acc[r], yv[t][r], bias_c);
                    float e   = __expf(-val);
                    float sv  = val * __builtin_amdgcn_rcpf(1.f + e);
                    sbuf[(t * 16 + bq * 4 + r) * SB_STRIDE + jt * 16 + m] = f2bf_fast(sv);
                }
            }
        } else {                // sigmoid -> gbuf, col (jt-24)*16+m
            #pragma unroll
            for (int t = 0; t < 2; ++t) {
                f32x4 acc = t ? acc1 : acc0;
                #pragma unroll
                for (int r = 0; r < 4; ++r) {
                    float val = fmaf(acc[r], yv[t][r], bias_c);
                    float e   = __expf(-val);
                    float sg  = __builtin_amdgcn_rcpf(1.f + e);
                    gbuf[(t * 16 + bq * 4 + r) * GB_STRIDE + (jt - 24) * 16 + m] = f2bf_fast(sg);
                }
            }
        }
        #pragma unroll
        for (int k = 0; k < 4; ++k) w0c[k] = w0n[k];
        bias_c = bias_n;
    }

    // ---- prefetch Phase-D weights (V0T) + bias before the barrier ----
    short8 v0f[12];
    {
        const short* v = WP + OFF_V0T + (wid * 16 + m) * 384 + bq * 8;
        #pragma unroll
        for (int k = 0; k < 12; ++k) v0f[k] = *(const short8*)(v + k * 32);
    }
    const float bo_r = bo[wid * 16 + m];
    __syncthreads();

    // ---- Phase D: o0(32x128) = s @ V0 ; 1 j-tile per wave ----
    {
        f32x4 accD0 = {0.f,0.f,0.f,0.f}, accD1 = {0.f,0.f,0.f,0.f};
        #pragma unroll
        for (int k = 0; k < 12; ++k) {
            short8 sa0 = *(const short8*)(sbuf + m * SB_STRIDE + k * 32 + bq * 8);
            short8 sa1 = *(const short8*)(sbuf + (16 + m) * SB_STRIDE + k * 32 + bq * 8);
            accD0 = MFMA(sa0, v0f[k], accD0);
            accD1 = MFMA(sa1, v0f[k], accD1);
        }
        #pragma unroll
        for (int t = 0; t < 2; ++t) {
            f32x4 acc = t ? accD1 : accD0;
            #pragma unroll
            for (int r = 0; r < 4; ++r)
                out[(size_t)(n0 + t * 16 + bq * 4 + r) * 480 + wid * 16 + m] =
                    fmaf(acc[r], yv[t][r], bo_r);
        }
    }

    // ---- prefetch B1 weights (hoisted across all 3 mm) ----
    short8 w1f[2][2];                   // [jj][k4], jt = wid + jj*8 (<12)
    #pragma unroll
    for (int jj = 0; jj < 2; ++jj) {
        const int jt = wid + jj * 8;
        if (jt < 12) {
            const short* w = WP + OFF_W1T + (jt * 16 + m) * 64 + bq * 8;
            w1f[jj][0] = *(const short8*)(w);
            w1f[jj][1] = *(const short8*)(w + 32);
        }
    }
    short8 v1f[6];                      // waves 4..7: V1T j-tile (wid-4)
    if (wid >= 4) {
        const short* v = WP + OFF_V1T + ((wid - 4) * 16 + m) * 192 + bq * 8;
        #pragma unroll
        for (int k = 0; k < 6; ++k) v1f[k] = *(const short8*)(v + k * 32);
    }
    __syncthreads();   // sbuf now dead; x1T region may be written

    // ---- stage x1 transposed: x1T[mm][node][u], u<64 pad 72 ----
    {
        const int node = tid >> 4, c16 = tid & 15;
        const float* xp = X + (size_t)(n0 + node) * 480 + 128 + c16 * 12;
        float4 fa = *(const float4*)xp;
        float4 fb = *(const float4*)(xp + 4);
        float4 fc = *(const float4*)(xp + 8);
        float vals[12] = {fa.x,fa.y,fa.z,fa.w, fb.x,fb.y,fb.z,fb.w, fc.x,fc.y,fc.z,fc.w};
        #pragma unroll
        for (int c = 0; c < 12; ++c) {
            const int u   = c16 * 4 + c / 3;    // static per c (c16*12 % 3 == 0)
            const int mmv = c % 3;
            x1T[mmv * 2304 + node * 72 + u] = f2bf_fast(vals[c]);
        }
    }
    __syncthreads();

    // ---- Phase B1: 3 components; GEMM1 (gate) -> ubuf; GEMM2 -> regs ----
    float o1a[3][2][4];                 // waves 4..7 accumulate all mm
    #pragma unroll
    for (int mm = 0; mm < 3; ++mm) {
        // GEMM1: v1_mm(32x192), j-tiles 0..11 (waves 0-3 take 2, 4-7 take 1)
        #pragma unroll
        for (int jj = 0; jj < 2; ++jj) {
            const int jt = wid + jj * 8;
            if (jt < 12) {
                f32x4 accA = {0.f,0.f,0.f,0.f}, accB = {0.f,0.f,0.f,0.f};
                short8 a00 = *(const short8*)(x1T + mm * 2304 + m * 72 + bq * 8);
                short8 a01 = *(const short8*)(x1T + mm * 2304 + m * 72 + 32 + bq * 8);
                short8 a10 = *(const short8*)(x1T + mm * 2304 + (16 + m) * 72 + bq * 8);
                short8 a11 = *(const short8*)(x1T + mm * 2304 + (16 + m) * 72 + 32 + bq * 8);
                accA = MFMA(a00, w1f[jj][0], accA);
                accA = MFMA(a01, w1f[jj][1], accA);
                accB = MFMA(a10, w1f[jj][0], accB);
                accB = MFMA(a11, w1f[jj][1], accB);
                #pragma unroll
                for (int t = 0; t < 2; ++t) {
                    f32x4 acc = t ? accB : accA;
                    #pragma unroll
                    for (int r = 0; r < 4; ++r) {
                        const int node = t * 16 + bq * 4 + r;
                        float gv = bf2f(gbuf[node * GB_STRIDE + jt * 16 + m]);
                        ubuf[node * UB_STRIDE + jt * 16 + m] =
                            f2bf_fast(acc[r] * yv[t][r] * gv);
                    }
                }
            }
        }
        __syncthreads();
        // GEMM2: o1_mm(32x64) = u @ V1 ; waves 4..7, j-tile (wid-4)
        if (wid >= 4) {
            f32x4 accA = {0.f,0.f,0.f,0.f}, accB = {0.f,0.f,0.f,0.f};
            #pragma unroll
            for (int k = 0; k < 6; ++k) {
                short8 au0 = *(const short8*)(ubuf + m * UB_STRIDE + k * 32 + bq * 8);
                short8 au1 = *(const short8*)(ubuf + (16 + m) * UB_STRIDE + k * 32 + bq * 8);
                accA = MFMA(au0, v1f[k], accA);
                accB = MFMA(au1, v1f[k], accB);
            }
            #pragma unroll
            for (int t = 0; t < 2; ++t) {
                f32x4 acc = t ? accB : accA;
                #pragma unroll
                for (int r = 0; r < 4; ++r)
                    o1a[mm][t][r] = acc[r] * yv[t][r];
            }
        }
        __syncthreads();
    }
    // dense o1 stores: 12B contiguous per lane per row
    if (wid >= 4) {
        const int jc = (wid - 4) * 16 + m;
        #pragma unroll
        for (int t = 0; t < 2; ++t)
            #pragma unroll
            for (int r = 0; r < 4; ++r) {
                float* p = out + (size_t)(n0 + t * 16 + bq * 4 + r) * 480 + 128 + jc * 3;
                p[0] = o1a[0][t][r]; p[1] = o1a[1][t][r]; p[2] = o1a[2][t][r];
            }
    }

    // ---- prefetch B2 weights ----
    short8 w2f;                          // waves 0..5: W2T j-tile wid
    if (wid < 6)
        w2f = *(const short8*)(WP + OFF_W2T + (wid * 16 + m) * 32 + bq * 8);
    short8 v2f[3];                       // waves 6..7: V2T j-tile (wid-6)
    if (wid >= 6) {
        const short* v = WP + OFF_V2T + ((wid - 6) * 16 + m) * 96 + bq * 8;
        #pragma unroll
        for (int k = 0; k < 3; ++k) v2f[k] = *(const short8*)(v + k * 32);
    }

    // ---- stage x2 transposed: x2T[mm][node][u], u<32 pad 40 ----
    {
        const int node = tid >> 4, c16 = tid & 15;
        const float* xp = X + (size_t)(n0 + node) * 480 + 320 + c16 * 10;
        float vals[10];
        #pragma unroll
        for (int p = 0; p < 5; ++p) {
            float2 f = *(const float2*)(xp + p * 2);
            vals[p * 2] = f.x; vals[p * 2 + 1] = f.y;
        }
        #pragma unroll
        for (int c = 0; c < 10; ++c) {
            const int u   = c16 * 2 + c / 5;    // static per c (c16*10 % 5 == 0)
            const int mmv = c % 5;
            x2T[mmv * 1280 + node * 40 + u] = f2bf_fast(vals[c]);
        }
    }
    __syncthreads();

    // ---- Phase B2: 5 components; GEMM1 (gate) -> ubuf; GEMM2 -> regs ----
    float o2a[5][2][4];                 // waves 6..7
    #pragma unroll
    for (int mm = 0; mm < 5; ++mm) {
        if (wid < 6) {                  // GEMM1: v2_mm(32x96), j-tile wid
            f32x4 accA = {0.f,0.f,0.f,0.f}, accB = {0.f,0.f,0.f,0.f};
            short8 a20 = *(const short8*)(x2T + mm * 1280 + m * 40 + bq * 8);
            short8 a21 = *(const short8*)(x2T + mm * 1280 + (16 + m) * 40 + bq * 8);
            accA = MFMA(a20, w2f, accA);
            accB = MFMA(a21, w2f, accB);
            #pragma unroll
            for (int t = 0; t < 2; ++t) {
                f32x4 acc = t ? accB : accA;
                #pragma unroll
                for (int r = 0; r < 4; ++r) {
                    const int node = t * 16 + bq * 4 + r;
                    float gv = bf2f(gbuf[node * GB_STRIDE + 192 + wid * 16 + m]);
                    ubuf[node * UB_STRIDE + wid * 16 + m] =
                        f2bf_fast(acc[r] * yv[t][r] * gv);
                }
            }
        }
        __syncthreads();
        if (wid >= 6) {                 // GEMM2: o2_mm(32x32) = u2 @ V2, K=96
            f32x4 accA = {0.f,0.f,0.f,0.f}, accB = {0.f,0.f,0.f,0.f};
            #pragma unroll
            for (int k = 0; k < 3; ++k) {
                short8 au0 = *(const short8*)(ubuf + m * UB_STRIDE + k * 32 + bq * 8);
                short8 au1 = *(const short8*)(ubuf + (16 + m) * UB_STRIDE + k * 32 + bq * 8);
                accA = MFMA(au0, v2f[k], accA);
                accB = MFMA(au1, v2f[k], accB);
            }
            #pragma unroll
            for (int t = 0; t < 2; ++t) {
                f32x4 acc = t ? accB : accA;
                #pragma unroll
                for (int r = 0; r < 4; ++r)
                    o2a[mm][t][r] = acc[r] * yv[t][r];
            }
        }
        if (mm < 4) __syncthreads();
    }
    // dense o2 stores: 20B contiguous per lane per row
    if (wid >= 6) {
        const int jc = (wid - 6) * 16 + m;
        #pragma unroll
        for (int t = 0; t < 2; ++t)
            #pragma unroll
            for (int r = 0; r < 4; ++r) {
                float* p = out + (size_t)(n0 + t * 16 + bq * 4 + r) * 480 + 320 + jc * 5;
                p[0] = o2a[0][t][r]; p[1] = o2a[1][t][r]; p[2] = o2a[2][t][r];
                p[3] = o2a[3][t][r]; p[4] = o2a[4][t][r];
            }
    }
}

extern "C" void kernel_launch(void* const* d_in, const int* in_sizes, int n_in,
                              void* d_out, int out_size, void* d_ws, size_t ws_size,
                              hipStream_t stream)
{
    const float* X   = (const float*)d_in[0];
    const float* Y   = (const float*)d_in[1];
    const float* W0s = (const float*)d_in[2];
    const float* bs  = (const float*)d_in[3];
    const float* W0g = (const float*)d_in[4];
    const float* bg  = (const float*)d_in[5];
    const float* W1  = (const float*)d_in[6];
    const float* W2  = (const float*)d_in[7];
    const float* V0  = (const float*)d_in[8];
    const float* bo  = (const float*)d_in[9];
    const float* V1  = (const float*)d_in[10];
    const float* V2  = (const float*)d_in[11];
    short* WP  = (short*)d_ws;           // 331776 B of bf16-packed weights
    float* out = (float*)d_out;

    const int n = in_sizes[0] / 480;     // 200000
    const int tiles = n / 32;            // 6250 32-node tiles (exact)

    prep_weights<<<dim3((WP_TOTAL + 255) / 256), dim3(256), 0, stream>>>(
        W0s, W0g, W1, W2, V0, V1, V2, WP);
    ffn_main<<<dim3(tiles), dim3(512), 0, stream>>>(X, Y, bs, bg, bo, WP, out);
}